// Round 11
// baseline (25.042 us; speedup 1.0000x reference)
//
#include <hip/hip_runtime.h>
#include <hip/hip_bf16.h>
#include <math.h>

// B=4, T=S=512, M=N=512, H=128
#define KDIM 512
#define HDIM 128
#define SDIM 512
#define INV_SCALE 0.04419417382415922f   // 1/sqrt(512)

// score[b,t,s] = a'[b,t] + c'[b,s]  (both pre-scaled)
//   a'[b,t] = inv_scale * sum_h v[h]   * tanh(q[b,t,:]·W2[h,:])
//   c'[b,s] = inv_scale * sum_h v[H+h] * tanh(k[b,s,:]·W1[h,:])
// D1: keys-proj -> c' in ws[0:2048]. D2: query-proj + fused output write.

typedef __attribute__((ext_vector_type(8))) short bf16x8;   // 8 bf16 = 4 VGPRs
typedef __attribute__((ext_vector_type(4))) float f32x4;    // MFMA accumulator

__device__ __forceinline__ float fast_tanh(float x) {
    // tanh(x) = 1 - 2/(e^{2x}+1); ~1e-7 abs error, graceful at +/-inf
    float e = __expf(2.0f * x);
    return 1.0f - 2.0f / (e + 1.0f);
}
__device__ __forceinline__ unsigned short bfbits(float x) {
    return __builtin_bit_cast(unsigned short, __float2bfloat16(x));
}

// k-bijection shared by A and B: lane-group g owns k-slots {g*4..g*4+3} u {16+g*4..19+g*4}
// within each 32-k step. This makes every f32 B half-frag load cover FULL 64B lines
// (lanes g=0..3 x float4 = one line per h-row), so no bf16 pre-conversion pass is needed.
//
// 512 threads (8 waves), 8 rows/block. Wave = h-tile h0 = 16*wave.
// A staged in LDS bf16 [8][512], 16B granule (t,g) XOR-swizzled by row&7.
// MFMA 16x16x32_bf16; C: row=(lane>>4)*4+reg (A-row), col=lane&15 (h). A-rows 8-15
// are fed duplicates of rows 0-7 (c16&7) -> C rows 8-15 harmless duplicates.
// Result: sm_a[r] = INV_SCALE * sum_h vv[h]*tanh(X[row0+r]·W[h]), r = 0..7.
__device__ __forceinline__ void proj_rows8(
    const float* __restrict__ X, const float* __restrict__ W,
    const float* __restrict__ vv, int row0,
    unsigned short* sm_x, float (*sm_p)[16], float* sm_a)
{
    const int tid  = threadIdx.x;
    const int wave = tid >> 6;
    const int lane = tid & 63;

    // ---- Stage X row (row0 + wave): 2 coalesced float4 loads/lane, cvt, swizzled b64 writes.
    {
        const float4* __restrict__ src = (const float4*)(X + (size_t)(row0 + wave) * KDIM);
        #pragma unroll
        for (int p = 0; p < 2; ++p) {
            const int f = p * 64 + lane;          // float4 index in row; k = 4f..4f+3
            const float4 xv = src[f];
            ushort4 o;
            o.x = bfbits(xv.x); o.y = bfbits(xv.y);
            o.z = bfbits(xv.z); o.w = bfbits(xv.w);
            const int t    = f >> 3;              // 32-k step
            const int off4 = f & 7;
            const int g    = off4 & 3;            // k-group
            const int half = off4 >> 2;           // 0: k-off 0-15, 1: k-off 16-31
            char* dst = (char*)sm_x + wave * 1024
                      + (((t * 4 + g) ^ (wave & 7)) << 4) + half * 8;
            *(ushort4*)dst = o;
        }
    }
    __syncthreads();

    const int c16 = lane & 15;
    const int g   = lane >> 4;
    const int h0  = wave * 16;
    const float* __restrict__ wrow = W + (size_t)(h0 + c16) * KDIM + g * 4;
    const char* __restrict__ arow = (const char*)sm_x + (c16 & 7) * 1024;
    const int swz = c16 & 7;

    f32x4 acc = {0.0f, 0.0f, 0.0f, 0.0f};
    #pragma unroll 4
    for (int t = 0; t < 16; ++t) {
        const float4 b0 = *(const float4*)(wrow + t * 32);        // k t*32 + g*4 ..+3
        const float4 b1 = *(const float4*)(wrow + t * 32 + 16);   // k t*32+16+g*4 ..+3
        const bf16x8 a = *(const bf16x8*)(arow + (((t * 4 + g) ^ swz) << 4));
        bf16x8 b;
        b[0] = bfbits(b0.x); b[1] = bfbits(b0.y);
        b[2] = bfbits(b0.z); b[3] = bfbits(b0.w);
        b[4] = bfbits(b1.x); b[5] = bfbits(b1.y);
        b[6] = bfbits(b1.z); b[7] = bfbits(b1.w);
        acc = __builtin_amdgcn_mfma_f32_16x16x32_bf16(a, b, acc, 0, 0, 0);
    }

    // acc[r] = dot(X[row0 + g*4 + r], W[h0 + c16])  (rows 8-15 duplicates)
    const float vh = vv[h0 + c16];
    #pragma unroll
    for (int r = 0; r < 4; ++r) {
        float s = vh * fast_tanh(acc[r]);
        s += __shfl_xor(s, 1, 64);   // reduce over h (lane bits 0-3)
        s += __shfl_xor(s, 2, 64);
        s += __shfl_xor(s, 4, 64);
        s += __shfl_xor(s, 8, 64);
        if (c16 == 0) sm_p[wave][g * 4 + r] = s;
    }
    __syncthreads();

    if (tid < 8) {
        float s = 0.0f;
        #pragma unroll
        for (int w = 0; w < 8; ++w) s += sm_p[w][tid];
        sm_a[tid] = s * INV_SCALE;
    }
    __syncthreads();
}

// D1: 256 blocks x 512 thr; block = 8 keys rows -> c' in ws[0:2048].
__global__ __launch_bounds__(512) void keys_kernel(
    const float* __restrict__ keys, const float* __restrict__ W1,
    const float* __restrict__ v, float* __restrict__ ws)
{
    __shared__ __align__(16) unsigned short sm_x[8 * KDIM];
    __shared__ float sm_p[8][16];
    __shared__ float sm_a[8];
    const int row0 = blockIdx.x * 8;
    proj_rows8(keys, W1, v + HDIM, row0, sm_x, sm_p, sm_a);
    if (threadIdx.x < 8) ws[row0 + threadIdx.x] = sm_a[threadIdx.x];
}

// D2: 256 blocks x 512 thr; block = 8 query rows; computes a' in LDS, then writes
// out[row][s] = a'[row] + c'[b][s] directly (outer kernel fused away).
__global__ __launch_bounds__(512) void query_out_kernel(
    const float* __restrict__ query, const float* __restrict__ W2,
    const float* __restrict__ v, const float* __restrict__ ws,
    float* __restrict__ out)
{
    __shared__ __align__(16) unsigned short sm_x[8 * KDIM];
    __shared__ float sm_p[8][16];
    __shared__ float sm_a[8];
    const int row0 = blockIdx.x * 8;
    const int tid  = threadIdx.x;

    // c' slice for this batch: issue early to hide LLC latency under the projection.
    const int b   = row0 >> 9;
    const int col = tid & 127;
    const float4 cv = ((const float4*)(ws + (size_t)b * SDIM))[col];

    proj_rows8(query, W2, v, row0, sm_x, sm_p, sm_a);

    // 4 thread-groups of 128 cover rows {0,1},{2,3},{4,5},{6,7}; float4 stores.
    const int rbase = (tid >> 7) * 2;
    #pragma unroll
    for (int rp = 0; rp < 2; ++rp) {
        const int r = rbase + rp;
        const float a = sm_a[r];
        float4 o;
        o.x = a + cv.x; o.y = a + cv.y; o.z = a + cv.z; o.w = a + cv.w;
        ((float4*)out)[(size_t)(row0 + r) * (SDIM / 4) + col] = o;
    }
}

extern "C" void kernel_launch(void* const* d_in, const int* in_sizes, int n_in,
                              void* d_out, int out_size, void* d_ws, size_t ws_size,
                              hipStream_t stream) {
    const float* query = (const float*)d_in[0];  // (4,512,512)
    const float* keys  = (const float*)d_in[1];  // (4,512,512)
    const float* W1    = (const float*)d_in[2];  // (128,512)
    const float* W2    = (const float*)d_in[3];  // (128,512)
    const float* v     = (const float*)d_in[4];  // (1,256)
    float* out = (float*)d_out;                  // (4,512,512) f32
    float* ws  = (float*)d_ws;                   // c' f32[2048]

    keys_kernel<<<256, 512, 0, stream>>>(keys, W1, v, ws);
    query_out_kernel<<<256, 512, 0, stream>>>(query, W2, v, ws, out);
}

// Round 12
// 21.930 us; speedup vs baseline: 1.1419x; 1.1419x over previous
//
#include <hip/hip_runtime.h>
#include <hip/hip_bf16.h>
#include <math.h>

// B=4, T=S=512, M=N=512, H=128
#define KDIM 512
#define HDIM 128
#define SDIM 512
#define INV_SCALE 0.04419417382415922f   // 1/sqrt(512)

// score[b,t,s] = a'[b,t] + c'[b,s]  (both pre-scaled)
//   a'[b,t] = inv_scale * sum_h v[h]   * tanh(q[b,t,:]·W2[h,:])
//   c'[b,s] = inv_scale * sum_h v[H+h] * tanh(k[b,s,:]·W1[h,:])
// ws layout: [0,2048) c' f32; [2048, 2048+32768) W2 bf16 [128][512] (ushort).
// D1: keys-proj (f32 W1, k-bijection) -> c'; side blocks convert W2 -> bf16.
// D2: query-proj (bf16 W2, r10 path) + fused output write.

typedef __attribute__((ext_vector_type(8))) short bf16x8;   // 8 bf16 = 4 VGPRs
typedef __attribute__((ext_vector_type(4))) float f32x4;    // MFMA accumulator

__device__ __forceinline__ float fast_tanh(float x) {
    // tanh(x) = 1 - 2/(e^{2x}+1); ~1e-7 abs error, graceful at +/-inf
    float e = __expf(2.0f * x);
    return 1.0f - 2.0f / (e + 1.0f);
}
__device__ __forceinline__ unsigned short bfbits(float x) {
    return __builtin_bit_cast(unsigned short, __float2bfloat16(x));
}

// ---------------- D1: keys projection (f32 W1) + W2 conversion ----------------
// blocks 0..127: 16 keys rows each. Wave = h-tile h0=16*wave. MFMA 16x16x32_bf16.
// k-bijection (r11-verified): lane-group g owns k-slots {t*32+g*4..+3} u {t*32+16+g*4..+3};
// A staged in LDS with matching granules, so f32 B half-frag loads cover FULL 64B lines.
// blocks 128..159: convert W2 (16384 float4) -> bf16 into ws.
__global__ __launch_bounds__(512) void keys_prep_kernel(
    const float* __restrict__ keys, const float* __restrict__ W1,
    const float* __restrict__ W2, const float* __restrict__ v,
    float* __restrict__ ws)
{
    const int blk = blockIdx.x;
    const int tid = threadIdx.x;

    if (blk >= 128) {
        // ---- W2 f32 -> bf16 (32 blocks x 512 thr x 1 float4) ----
        const int idx = (blk - 128) * 512 + tid;        // 0..16383
        const float4 w = ((const float4*)W2)[idx];
        ushort4 o;
        o.x = bfbits(w.x); o.y = bfbits(w.y); o.z = bfbits(w.z); o.w = bfbits(w.w);
        ((ushort4*)(ws + 2048))[idx] = o;
        return;
    }

    __shared__ __align__(16) unsigned short sm_x[16 * KDIM];  // 16 KB bf16
    __shared__ float sm_p[8][16];

    const int wave = tid >> 6;
    const int lane = tid & 63;
    const int row0 = blk * 16;
    const float* __restrict__ vv = v + HDIM;

    // ---- Stage X: wave handles rows {wave, wave+8}; granule matches k-bijection. ----
    #pragma unroll
    for (int it = 0; it < 2; ++it) {
        const int row = it * 8 + wave;
        const float4* __restrict__ src = (const float4*)(keys + (size_t)(row0 + row) * KDIM);
        #pragma unroll
        for (int p = 0; p < 2; ++p) {
            const int f = p * 64 + lane;          // float4 index; k = 4f..4f+3
            const float4 xv = src[f];
            ushort4 o;
            o.x = bfbits(xv.x); o.y = bfbits(xv.y);
            o.z = bfbits(xv.z); o.w = bfbits(xv.w);
            const int t    = f >> 3;              // 32-k step
            const int off4 = f & 7;
            const int g    = off4 & 3;            // k-group
            const int half = off4 >> 2;           // 0: k-off 0-15, 1: 16-31
            char* dst = (char*)sm_x + row * 1024
                      + (((t * 4 + g) ^ (row & 7)) << 4) + half * 8;
            *(ushort4*)dst = o;
        }
    }
    __syncthreads();

    const int c16 = lane & 15;
    const int g   = lane >> 4;
    const int h0  = wave * 16;
    const float* __restrict__ wrow = W1 + (size_t)(h0 + c16) * KDIM + g * 4;
    const char* __restrict__ arow = (const char*)sm_x + c16 * 1024;
    const int swz = c16 & 7;

    f32x4 acc = {0.0f, 0.0f, 0.0f, 0.0f};
    #pragma unroll 4
    for (int t = 0; t < 16; ++t) {
        const float4 b0 = *(const float4*)(wrow + t * 32);        // k t*32+g*4..+3
        const float4 b1 = *(const float4*)(wrow + t * 32 + 16);   // k t*32+16+g*4..+3
        const bf16x8 a = *(const bf16x8*)(arow + (((t * 4 + g) ^ swz) << 4));
        bf16x8 b;
        b[0] = bfbits(b0.x); b[1] = bfbits(b0.y);
        b[2] = bfbits(b0.z); b[3] = bfbits(b0.w);
        b[4] = bfbits(b1.x); b[5] = bfbits(b1.y);
        b[6] = bfbits(b1.z); b[7] = bfbits(b1.w);
        acc = __builtin_amdgcn_mfma_f32_16x16x32_bf16(a, b, acc, 0, 0, 0);
    }

    // acc[r] = dot(keys[row0+g*4+r], W1[h0+c16]); weight, tanh, reduce over h.
    const float vh = vv[h0 + c16];
    #pragma unroll
    for (int r = 0; r < 4; ++r) {
        float s = vh * fast_tanh(acc[r]);
        s += __shfl_xor(s, 1, 64);
        s += __shfl_xor(s, 2, 64);
        s += __shfl_xor(s, 4, 64);
        s += __shfl_xor(s, 8, 64);
        if (c16 == 0) sm_p[wave][g * 4 + r] = s;
    }
    __syncthreads();

    if (tid < 16) {
        float s = 0.0f;
        #pragma unroll
        for (int w = 0; w < 8; ++w) s += sm_p[w][tid];
        ws[row0 + tid] = s * INV_SCALE;   // c'
    }
}

// ---------------- D2: query projection (bf16 W2, r10 path) + fused out ----------------
// 128 blocks x 512 thr; 16 query rows/block. A staged bf16 LDS with r10 swizzle
// (slot ^= row&7); B-frags = contiguous bf16x8 from W2b (fully-used 64B lines).
__global__ __launch_bounds__(512) void query_out_kernel(
    const float* __restrict__ query, const float* __restrict__ ws,
    const float* __restrict__ v, float* __restrict__ out)
{
    __shared__ __align__(16) unsigned short sm_x[16 * KDIM];  // 16 KB
    __shared__ float sm_p[8][16];
    __shared__ float sm_a[16];

    const int tid  = threadIdx.x;
    const int wave = tid >> 6;
    const int lane = tid & 63;
    const int row0 = blockIdx.x * 16;
    const unsigned short* __restrict__ Wb = (const unsigned short*)(ws + 2048);

    // c' slice for this batch: issue early, consumed in the write phase.
    const int b   = row0 >> 9;
    const int col = tid & 127;
    const float4 cv = ((const float4*)ws)[b * 128 + col];

    // ---- Stage X tile (r10 layout): rows {wave, wave+8}, slot ^= row&7. ----
    #pragma unroll
    for (int it = 0; it < 2; ++it) {
        const int row = it * 8 + wave;
        const float4* __restrict__ src = (const float4*)(query + (size_t)(row0 + row) * KDIM);
        #pragma unroll
        for (int p = 0; p < 2; ++p) {
            const float4 xv = src[p * 64 + lane];
            ushort4 o;
            o.x = bfbits(xv.x); o.y = bfbits(xv.y);
            o.z = bfbits(xv.z); o.w = bfbits(xv.w);
            const int sl   = p * 32 + (lane >> 1);     // 16B slot in row
            const int half = lane & 1;
            char* dst = (char*)sm_x + row * 1024 + ((sl ^ (row & 7)) << 4) + half * 8;
            *(ushort4*)dst = o;
        }
    }
    __syncthreads();

    const int c16 = lane & 15;
    const int g   = lane >> 4;
    const int h0  = wave * 16;
    const unsigned short* __restrict__ wrow = Wb + (size_t)(h0 + c16) * KDIM + g * 8;
    const char* __restrict__ arow = (const char*)sm_x + c16 * 1024;
    const int swz = c16 & 7;

    f32x4 acc = {0.0f, 0.0f, 0.0f, 0.0f};
    #pragma unroll 4
    for (int t = 0; t < 16; ++t) {
        const bf16x8 a = *(const bf16x8*)(arow + (((t * 4 + g) ^ swz) << 4));
        const bf16x8 bb = *(const bf16x8*)(wrow + t * 32);
        acc = __builtin_amdgcn_mfma_f32_16x16x32_bf16(a, bb, acc, 0, 0, 0);
    }

    const float vh = v[h0 + c16];
    #pragma unroll
    for (int r = 0; r < 4; ++r) {
        float s = vh * fast_tanh(acc[r]);
        s += __shfl_xor(s, 1, 64);
        s += __shfl_xor(s, 2, 64);
        s += __shfl_xor(s, 4, 64);
        s += __shfl_xor(s, 8, 64);
        if (c16 == 0) sm_p[wave][g * 4 + r] = s;
    }
    __syncthreads();

    if (tid < 16) {
        float s = 0.0f;
        #pragma unroll
        for (int w = 0; w < 8; ++w) s += sm_p[w][tid];
        sm_a[tid] = s * INV_SCALE;   // a'
    }
    __syncthreads();

    // ---- Fused output: 4 groups of 128 threads x 4 rows; float4 stores. ----
    const int rbase = (tid >> 7) * 4;
    #pragma unroll
    for (int rp = 0; rp < 4; ++rp) {
        const int r = rbase + rp;
        const float a = sm_a[r];
        float4 o;
        o.x = a + cv.x; o.y = a + cv.y; o.z = a + cv.z; o.w = a + cv.w;
        ((float4*)out)[(size_t)(row0 + r) * (SDIM / 4) + col] = o;
    }
}

extern "C" void kernel_launch(void* const* d_in, const int* in_sizes, int n_in,
                              void* d_out, int out_size, void* d_ws, size_t ws_size,
                              hipStream_t stream) {
    const float* query = (const float*)d_in[0];  // (4,512,512)
    const float* keys  = (const float*)d_in[1];  // (4,512,512)
    const float* W1    = (const float*)d_in[2];  // (128,512)
    const float* W2    = (const float*)d_in[3];  // (128,512)
    const float* v     = (const float*)d_in[4];  // (1,256)
    float* out = (float*)d_out;                  // (4,512,512) f32
    float* ws  = (float*)d_ws;                   // c' f32[2048] + W2 bf16[65536]

    keys_prep_kernel<<<160, 512, 0, stream>>>(keys, W1, W2, v, ws);
    query_out_kernel<<<128, 512, 0, stream>>>(query, ws, v, out);
}

// Round 13
// 17.115 us; speedup vs baseline: 1.4632x; 1.2813x over previous
//
#include <hip/hip_runtime.h>
#include <hip/hip_bf16.h>
#include <math.h>

// B=4, T=S=512, M=N=512, H=128
#define KDIM 512
#define HDIM 128
#define SDIM 512
#define TOTAL_ROWS 2048
#define INV_SCALE 0.04419417382415922f   // 1/sqrt(512)

// score[b,t,s] = a'[b,t] + c'[b,s]  (both pre-scaled)
//   a'[b,t] = inv_scale * sum_h v[h]   * tanh(q[b,t,:]·W2[h,:])
//   c'[b,s] = inv_scale * sum_h v[H+h] * tanh(k[b,s,:]·W1[h,:])
// ws: [0,2048) a' f32 (query); [2048,4096) c' f32 (keys). No W conversion pass.
// D1: proj for BOTH sides, full chip (256 blocks), f32 W via k-bijection.
// D2: outer broadcast-add.

typedef __attribute__((ext_vector_type(8))) short bf16x8;   // 8 bf16 = 4 VGPRs
typedef __attribute__((ext_vector_type(4))) float f32x4;    // MFMA accumulator

__device__ __forceinline__ float fast_tanh(float x) {
    // tanh(x) = 1 - 2/(e^{2x}+1); ~1e-7 abs error, graceful at +/-inf
    float e = __expf(2.0f * x);
    return 1.0f - 2.0f / (e + 1.0f);
}
__device__ __forceinline__ unsigned short bfbits(float x) {
    return __builtin_bit_cast(unsigned short, __float2bfloat16(x));
}

// 256 blocks x 512 thr (8 waves): blk<128 query w/ W2 -> ws[0:2048);
// blk>=128 keys w/ W1 -> ws[2048:4096). 16 rows/block; wave = h-tile h0=16*wave.
// MFMA 16x16x32_bf16. Shared k-bijection (r11/r12-verified): within each 32-k step t,
// lane-group g = lane>>4 owns k-slots {t*32+g*4..+3} u {t*32+16+g*4..+3}; the two
// f32 B half-frag loads (lanes g=0..3 x float4) then cover FULL 64B lines per h-row,
// so W needs no bf16 pre-conversion. A staged in LDS bf16 with matching granules,
// XOR-swizzled by row&7 (conflict-free stage writes and frag reads).
// C layout: col = lane&15 (h), row = g*4 + reg (HW-verified r9/m89).
__global__ __launch_bounds__(512) void proj_kernel(
    const float* __restrict__ query, const float* __restrict__ keys,
    const float* __restrict__ W1, const float* __restrict__ W2,
    const float* __restrict__ v, float* __restrict__ ws)
{
    const int blk = blockIdx.x;
    const bool is_keys = (blk >= 128);
    const float* __restrict__ X  = is_keys ? keys : query;
    const float* __restrict__ Wf = is_keys ? W1 : W2;
    const float* __restrict__ vv = v + (is_keys ? HDIM : 0);
    float* __restrict__ out = ws + (is_keys ? TOTAL_ROWS : 0);
    const int row0 = (blk & 127) * 16;

    __shared__ __align__(16) unsigned short sm_x[16 * KDIM];  // 16 KB bf16
    __shared__ float sm_p[8][16];

    const int tid  = threadIdx.x;
    const int wave = tid >> 6;
    const int lane = tid & 63;

    // ---- Stage X: wave handles rows {wave, wave+8}; granule matches the k-bijection. ----
    #pragma unroll
    for (int it = 0; it < 2; ++it) {
        const int row = it * 8 + wave;
        const float4* __restrict__ src = (const float4*)(X + (size_t)(row0 + row) * KDIM);
        #pragma unroll
        for (int p = 0; p < 2; ++p) {
            const int f = p * 64 + lane;          // float4 index; k = 4f..4f+3
            const float4 xv = src[f];
            ushort4 o;
            o.x = bfbits(xv.x); o.y = bfbits(xv.y);
            o.z = bfbits(xv.z); o.w = bfbits(xv.w);
            const int t    = f >> 3;              // 32-k step
            const int off4 = f & 7;
            const int g    = off4 & 3;            // k-group
            const int half = off4 >> 2;           // 0: k-off 0-15, 1: 16-31
            char* dst = (char*)sm_x + row * 1024
                      + (((t * 4 + g) ^ (row & 7)) << 4) + half * 8;
            *(ushort4*)dst = o;
        }
    }
    __syncthreads();

    const int c16 = lane & 15;
    const int g   = lane >> 4;
    const int h0  = wave * 16;
    const float* __restrict__ wrow = Wf + (size_t)(h0 + c16) * KDIM + g * 4;
    const char* __restrict__ arow = (const char*)sm_x + c16 * 1024;
    const int swz = c16 & 7;

    f32x4 acc = {0.0f, 0.0f, 0.0f, 0.0f};
    #pragma unroll 4
    for (int t = 0; t < 16; ++t) {
        const float4 b0 = *(const float4*)(wrow + t * 32);        // k t*32+g*4..+3
        const float4 b1 = *(const float4*)(wrow + t * 32 + 16);   // k t*32+16+g*4..+3
        const bf16x8 a = *(const bf16x8*)(arow + (((t * 4 + g) ^ swz) << 4));
        bf16x8 b;
        b[0] = bfbits(b0.x); b[1] = bfbits(b0.y);
        b[2] = bfbits(b0.z); b[3] = bfbits(b0.w);
        b[4] = bfbits(b1.x); b[5] = bfbits(b1.y);
        b[6] = bfbits(b1.z); b[7] = bfbits(b1.w);
        acc = __builtin_amdgcn_mfma_f32_16x16x32_bf16(a, b, acc, 0, 0, 0);
    }

    // acc[r] = dot(X[row0+g*4+r], W[h0+c16]); weight by v, tanh, reduce over h.
    const float vh = vv[h0 + c16];
    #pragma unroll
    for (int r = 0; r < 4; ++r) {
        float s = vh * fast_tanh(acc[r]);
        s += __shfl_xor(s, 1, 64);
        s += __shfl_xor(s, 2, 64);
        s += __shfl_xor(s, 4, 64);
        s += __shfl_xor(s, 8, 64);
        if (c16 == 0) sm_p[wave][g * 4 + r] = s;
    }
    __syncthreads();

    if (tid < 16) {
        float s = 0.0f;
        #pragma unroll
        for (int w = 0; w < 8; ++w) s += sm_p[w][tid];
        out[row0 + tid] = s * INV_SCALE;
    }
}

// 256 blocks x 256 thr; block = 8 bt-rows (single batch each). c' row stays L1-hot.
__global__ __launch_bounds__(256) void outer_kernel(
    const float* __restrict__ ws, float* __restrict__ out)
{
    const int r0  = blockIdx.x * 8;
    const int b   = r0 >> 9;
    const float4* __restrict__ c4 = (const float4*)(ws + TOTAL_ROWS + (size_t)b * SDIM);
    const int col = threadIdx.x & 127;
    const int rh  = threadIdx.x >> 7;   // 0/1

    #pragma unroll
    for (int rp = 0; rp < 4; ++rp) {
        const int row = r0 + rp * 2 + rh;
        const float a = ws[row];
        const float4 c = c4[col];
        float4 o;
        o.x = a + c.x; o.y = a + c.y; o.z = a + c.z; o.w = a + c.w;
        ((float4*)out)[(size_t)row * (SDIM / 4) + col] = o;
    }
}

extern "C" void kernel_launch(void* const* d_in, const int* in_sizes, int n_in,
                              void* d_out, int out_size, void* d_ws, size_t ws_size,
                              hipStream_t stream) {
    const float* query = (const float*)d_in[0];  // (4,512,512)
    const float* keys  = (const float*)d_in[1];  // (4,512,512)
    const float* W1    = (const float*)d_in[2];  // (128,512)
    const float* W2    = (const float*)d_in[3];  // (128,512)
    const float* v     = (const float*)d_in[4];  // (1,256)
    float* out = (float*)d_out;                  // (4,512,512) f32
    float* ws  = (float*)d_ws;                   // a' + c' (4096 floats)

    proj_kernel<<<256, 512, 0, stream>>>(query, keys, W1, W2, v, ws);
    outer_kernel<<<256, 256, 0, stream>>>(ws, out);
}